// Round 8
// baseline (317.397 us; speedup 1.0000x reference)
//
#include <hip/hip_runtime.h>
#include <stdint.h>

#define NN 100000
#define NE 50000
#define NBLK 256   // blocks in binning phases
#define NBK 196    // buckets (both orientations)
#define ESH 8      // 256 edge targets / bucket
#define NSH 9      // 512 node targets / bucket

using bf16x8 = __attribute__((ext_vector_type(8))) short;
using f32x4  = __attribute__((ext_vector_type(4))) float;

__device__ inline unsigned f2bf(float f) {
  union { float f; unsigned u; } x; x.f = f;
  unsigned u = x.u;
  return (u + 0x7FFFu + ((u >> 16) & 1u)) >> 16;  // RNE, low 16 bits valid
}
__device__ inline float bfbits2f(unsigned bits) {  // bits already high-half
  union { unsigned u; float f; } x; x.u = bits;
  return x.f;
}

// ---------------- CSR build: two-level counting sort ----------------

__global__ __launch_bounds__(256) void hist_kernel(const int* __restrict__ nidx,
                                                   const int* __restrict__ eidx, int ni,
                                                   int* __restrict__ He, int* __restrict__ Hn) {
  __shared__ int he[NBK], hn[NBK];
  for (int t = threadIdx.x; t < NBK; t += 256) { he[t] = 0; hn[t] = 0; }
  __syncthreads();
  int chunk = (ni + NBLK - 1) / NBLK;
  int s = blockIdx.x * chunk, e = min(s + chunk, ni);
  for (int i = s + threadIdx.x; i < e; i += 256) {
    atomicAdd(&he[eidx[i] >> ESH], 1);
    atomicAdd(&hn[nidx[i] >> NSH], 1);
  }
  __syncthreads();
  for (int t = threadIdx.x; t < NBK; t += 256) {
    He[t * NBLK + blockIdx.x] = he[t];
    Hn[t * NBLK + blockIdx.x] = hn[t];
  }
}

__global__ __launch_bounds__(256) void scanH_kernel(int* __restrict__ He, int* __restrict__ Hn,
                                                    int* __restrict__ ebb, int* __restrict__ nbb,
                                                    int ni) {
  int* H = blockIdx.x ? Hn : He;
  int* bb = blockIdx.x ? nbb : ebb;
  __shared__ int tot[256];
  int t = threadIdx.x;
  int sum = 0;
  if (t < NBK)
    for (int b = 0; b < NBLK; b++) sum += H[t * NBLK + b];
  tot[t] = sum;
  __syncthreads();
  for (int o = 1; o < 256; o <<= 1) {
    int v = (t >= o) ? tot[t - o] : 0;
    __syncthreads();
    tot[t] += v;
    __syncthreads();
  }
  int base = (t > 0) ? tot[t - 1] : 0;
  if (t < NBK) {
    bb[t] = base;
    int run = base;
    for (int b = 0; b < NBLK; b++) {
      int old = H[t * NBLK + b];
      H[t * NBLK + b] = run;
      run += old;
    }
  }
  if (t == 0) bb[NBK] = ni;
}

__global__ __launch_bounds__(256) void scatter_kernel(const int* __restrict__ nidx,
                                                      const int* __restrict__ eidx, int ni,
                                                      const int* __restrict__ He,
                                                      const int* __restrict__ Hn,
                                                      int2* __restrict__ binE,
                                                      int2* __restrict__ binN) {
  __shared__ int ce[NBK], cn[NBK];
  for (int t = threadIdx.x; t < NBK; t += 256) {
    ce[t] = He[t * NBLK + blockIdx.x];
    cn[t] = Hn[t * NBLK + blockIdx.x];
  }
  __syncthreads();
  int chunk = (ni + NBLK - 1) / NBLK;
  int s = blockIdx.x * chunk, e = min(s + chunk, ni);
  for (int i = s + threadIdx.x; i < e; i += 256) {
    int nd = nidx[i], ed = eidx[i];
    int pe = atomicAdd(&ce[ed >> ESH], 1);
    binE[pe] = make_int2(nd, ed);
    int pn = atomicAdd(&cn[nd >> NSH], 1);
    binN[pn] = make_int2(ed, nd);
  }
}

__global__ __launch_bounds__(256) void finalize_kernel(const int2* __restrict__ binE,
                                                       const int2* __restrict__ binN,
                                                       const int* __restrict__ ebb,
                                                       const int* __restrict__ nbb,
                                                       int* __restrict__ eoff, int* __restrict__ noff,
                                                       float* __restrict__ einv, float* __restrict__ ninv,
                                                       int* __restrict__ edge_nodes,
                                                       int* __restrict__ node_edges, int ni) {
  __shared__ int cnt[512], excl[512], sc[256];
  bool isE = blockIdx.x < NBK;
  int b = isE ? blockIdx.x : blockIdx.x - NBK;
  const int2* bin = isE ? binE : binN;
  const int* bb = isE ? ebb : nbb;
  int* off = isE ? eoff : noff;
  float* inv = isE ? einv : ninv;
  int* out = isE ? edge_nodes : node_edges;
  int NT = isE ? NE : NN;
  int sh = isE ? ESH : NSH;
  int tbase = b << sh;
  int nt = min(1 << sh, NT - tbase);
  int t = threadIdx.x;
  cnt[t] = 0; cnt[t + 256] = 0;
  __syncthreads();
  int s = bb[b], e = bb[b + 1];
  for (int i = s + t; i < e; i += 256) atomicAdd(&cnt[bin[i].y - tbase], 1);
  __syncthreads();
  int p = cnt[2 * t] + cnt[2 * t + 1];
  sc[t] = p;
  __syncthreads();
  for (int o = 1; o < 256; o <<= 1) {
    int v = (t >= o) ? sc[t - o] : 0;
    __syncthreads();
    sc[t] += v;
    __syncthreads();
  }
  int pb = (t > 0) ? sc[t - 1] : 0;
  excl[2 * t] = pb;
  excl[2 * t + 1] = pb + cnt[2 * t];
  __syncthreads();
  for (int lt = t; lt < nt; lt += 256) {
    off[tbase + lt] = s + excl[lt];
    int c = cnt[lt];
    inv[tbase + lt] = (c > 0) ? 1.0f / (float)c : 0.0f;
  }
  if (b == NBK - 1 && t == 0) off[NT] = ni;
  __syncthreads();
  cnt[t] = 0; cnt[t + 256] = 0;
  __syncthreads();
  for (int i = s + t; i < e; i += 256) {
    int2 it = bin[i];
    int lt = it.y - tbase;
    int pos = s + excl[lt] + atomicAdd(&cnt[lt], 1);
    out[pos] = it.x;
  }
}

// ---------------- weights pack (bf16 MFMA B-fragment order) ----------------
__global__ void packw_kernel(const float* __restrict__ w0, const float* __restrict__ w1,
                             const float* __restrict__ w2, const float* __restrict__ w3,
                             short* __restrict__ wp) {
  int gid = blockIdx.x * blockDim.x + threadIdx.x;
  if (gid >= 4 * 16384) return;
  int w = gid >> 14, r = gid & 16383;
  int j = r & 7, lane = (r >> 3) & 63, kk = (r >> 9) & 3, ct = (r >> 11) & 7;
  int k = kk * 32 + (lane >> 4) * 8 + j;
  int c = ct * 16 + (lane & 15);
  const float* W = (w == 0) ? w0 : (w == 1) ? w1 : (w == 2) ? w2 : w3;
  wp[gid] = (short)f2bf(W[k * 128 + c]);
}

// ---------------- cvt: x f32 [NN][128] -> bf16 half-split [2][NN][64] ----------------
__global__ __launch_bounds__(256) void cvtsplit_kernel(const float* __restrict__ x,
                                                       uint4* __restrict__ xb) {
  size_t q = (size_t)blockIdx.x * 256 + threadIdx.x;  // one uint4 (8 bf16)
  size_t row = q >> 4;
  int seg = (int)(q & 15);           // 8-float segment within the 128-dim row
  int plane = seg >> 3, within = seg & 7;
  const float4* xf = (const float4*)x;
  float4 lo = xf[q * 2], hi = xf[q * 2 + 1];
  uint4 o;
  o.x = (f2bf(lo.x) & 0xffffu) | (f2bf(lo.y) << 16);
  o.y = (f2bf(lo.z) & 0xffffu) | (f2bf(lo.w) << 16);
  o.z = (f2bf(hi.x) & 0xffffu) | (f2bf(hi.y) << 16);
  o.w = (f2bf(hi.z) & 0xffffu) | (f2bf(hi.w) << 16);
  xb[((size_t)plane * NN + row) * 8 + within] = o;
}

// ---------------- half-plane gather ----------------
// src: bf16 half-split [2][Rsrc][64] (uint4 granules, 8 per row-half).
// Processes plane h only: per-pass random working set = Rsrc*128B (half).
// 8 lanes/target x 16B; 32 targets/block. 8-way MLP unroll.
// OBF: dst bf16 half-split [2][T][64]; else dst f32 row-major [T][128] (half h cols).
template <bool PRELU, bool OBF>
__global__ __launch_bounds__(256) void gatherh_kernel(const uint4* __restrict__ src,
                                                      void* __restrict__ dst,
                                                      const int* __restrict__ off,
                                                      const int* __restrict__ ids,
                                                      const float* __restrict__ inv,
                                                      const float* __restrict__ bias,
                                                      const float* __restrict__ alpha_p,
                                                      int T, int Rsrc, int h) {
  int tgt = blockIdx.x * 32 + (threadIdx.x >> 3);
  if (tgt >= T) return;
  int c = threadIdx.x & 7;
  int s = off[tgt], e = off[tgt + 1];
  const uint4* base = src + (size_t)h * Rsrc * 8 + c;
  float r[8] = {0, 0, 0, 0, 0, 0, 0, 0};
  int i = s;
  for (; i + 8 <= e; i += 8) {
    int idv[8];
#pragma unroll
    for (int u = 0; u < 8; u++) idv[u] = ids[i + u];
    uint4 v[8];
#pragma unroll
    for (int u = 0; u < 8; u++) v[u] = base[(size_t)idv[u] * 8];
#pragma unroll
    for (int u = 0; u < 8; u++) {
      r[0] += bfbits2f(v[u].x << 16); r[1] += bfbits2f(v[u].x & 0xffff0000u);
      r[2] += bfbits2f(v[u].y << 16); r[3] += bfbits2f(v[u].y & 0xffff0000u);
      r[4] += bfbits2f(v[u].z << 16); r[5] += bfbits2f(v[u].z & 0xffff0000u);
      r[6] += bfbits2f(v[u].w << 16); r[7] += bfbits2f(v[u].w & 0xffff0000u);
    }
  }
  for (; i < e; i++) {
    uint4 v = base[(size_t)ids[i] * 8];
    r[0] += bfbits2f(v.x << 16); r[1] += bfbits2f(v.x & 0xffff0000u);
    r[2] += bfbits2f(v.y << 16); r[3] += bfbits2f(v.y & 0xffff0000u);
    r[4] += bfbits2f(v.z << 16); r[5] += bfbits2f(v.z & 0xffff0000u);
    r[6] += bfbits2f(v.w << 16); r[7] += bfbits2f(v.w & 0xffff0000u);
  }
  float scv = inv[tgt];
  float al = PRELU ? *alpha_p : 0.f;
  float b[8] = {0, 0, 0, 0, 0, 0, 0, 0};
  if (bias) {
    float4 b0 = ((const float4*)bias)[h * 16 + c * 2];
    float4 b1 = ((const float4*)bias)[h * 16 + c * 2 + 1];
    b[0] = b0.x; b[1] = b0.y; b[2] = b0.z; b[3] = b0.w;
    b[4] = b1.x; b[5] = b1.y; b[6] = b1.z; b[7] = b1.w;
  }
#pragma unroll
  for (int j = 0; j < 8; j++) {
    float v = r[j] * scv + b[j];
    if constexpr (PRELU) v = (v >= 0.f) ? v : al * v;
    r[j] = v;
  }
  if constexpr (OBF) {
    uint4 o;
    o.x = (f2bf(r[0]) & 0xffffu) | (f2bf(r[1]) << 16);
    o.y = (f2bf(r[2]) & 0xffffu) | (f2bf(r[3]) << 16);
    o.z = (f2bf(r[4]) & 0xffffu) | (f2bf(r[5]) << 16);
    o.w = (f2bf(r[6]) & 0xffffu) | (f2bf(r[7]) << 16);
    ((uint4*)dst)[((size_t)h * T + tgt) * 8 + c] = o;
  } else {
    float4 o0; o0.x = r[0]; o0.y = r[1]; o0.z = r[2]; o0.w = r[3];
    float4 o1; o1.x = r[4]; o1.y = r[5]; o1.z = r[6]; o1.w = r[7];
    ((float4*)dst)[(size_t)tgt * 32 + h * 16 + c * 2] = o0;
    ((float4*)dst)[(size_t)tgt * 32 + h * 16 + c * 2 + 1] = o1;
  }
}

// ---------------- fused double-GEMM: e = prelu(A@WA); xn = e@WB ----------------
// A, xn in bf16 half-split [2][M][64]. Wave-private LDS transpose between the
// GEMMs (wave w owns tile rows w*16..w*16+15) -> no barriers. WEF32: also
// write e as f32 row-major [M][128] (layer-2 edge output).
template <bool WEF32>
__global__ __launch_bounds__(256) void gemm12_kernel(const short* __restrict__ A,
                                                     const short* __restrict__ wpA,
                                                     const short* __restrict__ wpB,
                                                     const float* __restrict__ alpha_p,
                                                     short* __restrict__ xn,
                                                     float* __restrict__ eoutf, int M) {
  __shared__ short tile[64][136];
  int wave = threadIdx.x >> 6;
  int lane = threadIdx.x & 63;
  int kg = lane >> 4;
  int rloc = lane & 15;
  int base = blockIdx.x * 64;
  int row = base + wave * 16 + rloc;
  float al = *alpha_p;

  bf16x8 a[4];
  if (row < M) {
    const short* p0 = A + (size_t)row * 64 + kg * 8;
    const short* p1 = A + ((size_t)M + row) * 64 + kg * 8;
    a[0] = *(const bf16x8*)p0;
    a[1] = *(const bf16x8*)(p0 + 32);
    a[2] = *(const bf16x8*)p1;
    a[3] = *(const bf16x8*)(p1 + 32);
  } else {
#pragma unroll
    for (int kk = 0; kk < 4; kk++) a[kk] = bf16x8{0, 0, 0, 0, 0, 0, 0, 0};
  }

  // GEMM1 + prelu
#pragma unroll
  for (int ct = 0; ct < 8; ct++) {
    f32x4 acc = {0.f, 0.f, 0.f, 0.f};
#pragma unroll
    for (int kk = 0; kk < 4; kk++) {
      bf16x8 bfr = *(const bf16x8*)(wpA + ((size_t)(ct * 4 + kk) * 64 + lane) * 8);
      acc = __builtin_amdgcn_mfma_f32_16x16x32_bf16(a[kk], bfr, acc, 0, 0, 0);
    }
    int col = ct * 16 + rloc;
#pragma unroll
    for (int j = 0; j < 4; j++) {
      float v = acc[j];
      v = (v >= 0.f) ? v : al * v;
      int lrow = wave * 16 + kg * 4 + j;
      int grow = base + lrow;
      if (WEF32 && grow < M) eoutf[(size_t)grow * 128 + col] = v;
      tile[lrow][col] = (short)f2bf(v);
    }
  }

  // GEMM2 from wave-private LDS tile
  bf16x8 a2[4];
#pragma unroll
  for (int kk = 0; kk < 4; kk++)
    a2[kk] = *(const bf16x8*)&tile[wave * 16 + rloc][kg * 8 + kk * 32];
#pragma unroll
  for (int ct = 0; ct < 8; ct++) {
    f32x4 acc = {0.f, 0.f, 0.f, 0.f};
#pragma unroll
    for (int kk = 0; kk < 4; kk++) {
      bf16x8 bfr = *(const bf16x8*)(wpB + ((size_t)(ct * 4 + kk) * 64 + lane) * 8);
      acc = __builtin_amdgcn_mfma_f32_16x16x32_bf16(a2[kk], bfr, acc, 0, 0, 0);
    }
    int plane = ct >> 2;
    int colh = (ct & 3) * 16 + rloc;
#pragma unroll
    for (int j = 0; j < 4; j++) {
      int grow = base + wave * 16 + kg * 4 + j;
      if (grow < M) xn[((size_t)plane * M + grow) * 64 + colh] = (short)f2bf(acc[j]);
    }
  }
}

extern "C" void kernel_launch(void* const* d_in, const int* in_sizes, int n_in,
                              void* d_out, int out_size, void* d_ws, size_t ws_size,
                              hipStream_t stream) {
  const float* x = (const float*)d_in[0];
  const int* nidx = (const int*)d_in[1];
  int NI = in_sizes[1] / 2;
  const int* eidx = nidx + NI;
  const float* W0 = (const float*)d_in[2];
  const float* W1 = (const float*)d_in[3];
  const float* b0 = (const float*)d_in[4];
  const float* W2 = (const float*)d_in[5];
  const float* W3 = (const float*)d_in[6];
  const float* b1 = (const float*)d_in[7];
  const float* alpha = (const float*)d_in[8];

  char* ws = (char*)d_ws;
  size_t o = 0;
  auto alloc = [&](size_t bytes) { void* p = ws + o; o += (bytes + 255) & ~255ull; return p; };
  int* He = (int*)alloc((size_t)NBK * NBLK * 4);
  int* Hn = (int*)alloc((size_t)NBK * NBLK * 4);
  int* ebb = (int*)alloc((NBK + 1) * 4);
  int* nbb = (int*)alloc((NBK + 1) * 4);
  int* eoff = (int*)alloc((size_t)(NE + 1) * 4);
  int* noff = (int*)alloc((size_t)(NN + 1) * 4);
  float* einv = (float*)alloc((size_t)NE * 4);
  float* ninv = (float*)alloc((size_t)NN * 4);
  int* edge_nodes = (int*)alloc((size_t)NI * 4);
  int* node_edges = (int*)alloc((size_t)NI * 4);
  short* wp = (short*)alloc((size_t)4 * 16384 * 2);
  // arena: bins (CSR build, 16MB) alias xb (25.6MB, written after CSR build)
  char* arena = (char*)alloc((size_t)NN * 128 * 2 + (size_t)NE * 128 * 2 * 2);
  int2* binE = (int2*)arena;
  int2* binN = (int2*)(arena + (size_t)NI * 8);
  short* xb = (short*)arena;                           // [2][NN][64] bf16; n1 aliases later
  short* Ge = (short*)(arena + (size_t)NN * 128 * 2);  // [2][NE][64] bf16 (aggregated)
  short* xn = (short*)(arena + (size_t)NN * 128 * 2 + (size_t)NE * 128 * 2);  // [2][NE][64]

  float* outN = (float*)d_out;
  float* outE = outN + (size_t)NN * 128;

  // CSR build (both orientations)
  hist_kernel<<<NBLK, 256, 0, stream>>>(nidx, eidx, NI, He, Hn);
  scanH_kernel<<<2, 256, 0, stream>>>(He, Hn, ebb, nbb, NI);
  scatter_kernel<<<NBLK, 256, 0, stream>>>(nidx, eidx, NI, He, Hn, binE, binN);
  finalize_kernel<<<2 * NBK, 256, 0, stream>>>(binE, binN, ebb, nbb, eoff, noff,
                                               einv, ninv, edge_nodes, node_edges, NI);
  packw_kernel<<<256, 256, 0, stream>>>(W0, W1, W2, W3, wp);
  cvtsplit_kernel<<<NN * 128 / 8 / 256, 256, 0, stream>>>(x, (uint4*)xb);

  int ggE = (NE + 31) / 32;   // 1563 blocks per half-pass
  int ggN = (NN + 31) / 32;   // 3125
  int gfE = (NE + 63) / 64;   // 782

  // layer 1
  gatherh_kernel<false, true><<<ggE, 256, 0, stream>>>((const uint4*)xb, Ge, eoff, edge_nodes,
                                                       einv, nullptr, alpha, NE, NN, 0);
  gatherh_kernel<false, true><<<ggE, 256, 0, stream>>>((const uint4*)xb, Ge, eoff, edge_nodes,
                                                       einv, nullptr, alpha, NE, NN, 1);
  gemm12_kernel<false><<<gfE, 256, 0, stream>>>(Ge, wp + 0 * 16384, wp + 1 * 16384,
                                                alpha, xn, nullptr, NE);
  short* n1 = xb;  // x~ dead after layer-1 e-gather
  gatherh_kernel<true, true><<<ggN, 256, 0, stream>>>((const uint4*)xn, n1, noff, node_edges,
                                                      ninv, b0, alpha, NN, NE, 0);
  gatherh_kernel<true, true><<<ggN, 256, 0, stream>>>((const uint4*)xn, n1, noff, node_edges,
                                                      ninv, b0, alpha, NN, NE, 1);
  // layer 2
  gatherh_kernel<false, true><<<ggE, 256, 0, stream>>>((const uint4*)n1, Ge, eoff, edge_nodes,
                                                       einv, nullptr, alpha, NE, NN, 0);
  gatherh_kernel<false, true><<<ggE, 256, 0, stream>>>((const uint4*)n1, Ge, eoff, edge_nodes,
                                                       einv, nullptr, alpha, NE, NN, 1);
  gemm12_kernel<true><<<gfE, 256, 0, stream>>>(Ge, wp + 2 * 16384, wp + 3 * 16384,
                                               alpha, xn, outE, NE);
  gatherh_kernel<true, false><<<ggN, 256, 0, stream>>>((const uint4*)xn, outN, noff, node_edges,
                                                       ninv, b1, alpha, NN, NE, 0);
  gatherh_kernel<true, false><<<ggN, 256, 0, stream>>>((const uint4*)xn, outN, noff, node_edges,
                                                       ninv, b1, alpha, NN, NE, 1);
}

// Round 9
// 288.201 us; speedup vs baseline: 1.1013x; 1.1013x over previous
//
#include <hip/hip_runtime.h>
#include <stdint.h>

#define NN 100000
#define NE 50000
#define NBLK 256   // blocks in binning phases
#define NBK 196    // buckets (both orientations)
#define ESH 8      // 256 edge targets / bucket
#define NSH 9      // 512 node targets / bucket

using bf16x8 = __attribute__((ext_vector_type(8))) short;
using f32x4  = __attribute__((ext_vector_type(4))) float;

__device__ inline unsigned f2bf(float f) {
  union { float f; unsigned u; } x; x.f = f;
  unsigned u = x.u;
  return (u + 0x7FFFu + ((u >> 16) & 1u)) >> 16;  // RNE, low 16 bits valid
}
__device__ inline float bfbits2f(unsigned bits) {  // bits already high-half
  union { unsigned u; float f; } x; x.u = bits;
  return x.f;
}

// ---------------- CSR build: two-level counting sort, packed 4B bins ----------------
// binE entry: node_src (bits 0..16) | edge_local (bits 17..24), bucket = 256 edges
// binN entry: edge_src (bits 0..15) | node_local (bits 16..24), bucket = 512 nodes

__global__ __launch_bounds__(256) void hist_kernel(const int* __restrict__ nidx,
                                                   const int* __restrict__ eidx, int ni,
                                                   int* __restrict__ He, int* __restrict__ Hn) {
  __shared__ int he[NBK], hn[NBK];
  for (int t = threadIdx.x; t < NBK; t += 256) { he[t] = 0; hn[t] = 0; }
  __syncthreads();
  int chunk = (ni + NBLK - 1) / NBLK;
  int s = blockIdx.x * chunk, e = min(s + chunk, ni);
  for (int i = s + threadIdx.x; i < e; i += 256) {
    atomicAdd(&he[eidx[i] >> ESH], 1);
    atomicAdd(&hn[nidx[i] >> NSH], 1);
  }
  __syncthreads();
  for (int t = threadIdx.x; t < NBK; t += 256) {
    He[t * NBLK + blockIdx.x] = he[t];
    Hn[t * NBLK + blockIdx.x] = hn[t];
  }
}

__global__ __launch_bounds__(256) void scanH_kernel(int* __restrict__ He, int* __restrict__ Hn,
                                                    int* __restrict__ ebb, int* __restrict__ nbb,
                                                    int ni) {
  int* H = blockIdx.x ? Hn : He;
  int* bb = blockIdx.x ? nbb : ebb;
  __shared__ int tot[256];
  int t = threadIdx.x;
  int sum = 0;
  if (t < NBK)
    for (int b = 0; b < NBLK; b++) sum += H[t * NBLK + b];
  tot[t] = sum;
  __syncthreads();
  for (int o = 1; o < 256; o <<= 1) {
    int v = (t >= o) ? tot[t - o] : 0;
    __syncthreads();
    tot[t] += v;
    __syncthreads();
  }
  int base = (t > 0) ? tot[t - 1] : 0;
  if (t < NBK) {
    bb[t] = base;
    int run = base;
    for (int b = 0; b < NBLK; b++) {
      int old = H[t * NBLK + b];
      H[t * NBLK + b] = run;
      run += old;
    }
  }
  if (t == 0) bb[NBK] = ni;
}

__global__ __launch_bounds__(256) void scatter_kernel(const int* __restrict__ nidx,
                                                      const int* __restrict__ eidx, int ni,
                                                      const int* __restrict__ He,
                                                      const int* __restrict__ Hn,
                                                      unsigned* __restrict__ binE,
                                                      unsigned* __restrict__ binN) {
  __shared__ int ce[NBK], cn[NBK];
  for (int t = threadIdx.x; t < NBK; t += 256) {
    ce[t] = He[t * NBLK + blockIdx.x];
    cn[t] = Hn[t * NBLK + blockIdx.x];
  }
  __syncthreads();
  int chunk = (ni + NBLK - 1) / NBLK;
  int s = blockIdx.x * chunk, e = min(s + chunk, ni);
  for (int i = s + threadIdx.x; i < e; i += 256) {
    int nd = nidx[i], ed = eidx[i];
    int pe = atomicAdd(&ce[ed >> ESH], 1);
    binE[pe] = (unsigned)nd | ((unsigned)(ed & 255) << 17);
    int pn = atomicAdd(&cn[nd >> NSH], 1);
    binN[pn] = (unsigned)ed | ((unsigned)(nd & 511) << 16);
  }
}

__global__ __launch_bounds__(256) void finalize_kernel(const unsigned* __restrict__ binE,
                                                       const unsigned* __restrict__ binN,
                                                       const int* __restrict__ ebb,
                                                       const int* __restrict__ nbb,
                                                       int* __restrict__ eoff, int* __restrict__ noff,
                                                       float* __restrict__ einv, float* __restrict__ ninv,
                                                       int* __restrict__ edge_nodes,
                                                       int* __restrict__ node_edges, int ni) {
  __shared__ int cnt[512], excl[512], sc[256];
  bool isE = blockIdx.x < NBK;
  int b = isE ? blockIdx.x : blockIdx.x - NBK;
  const unsigned* bin = isE ? binE : binN;
  const int* bb = isE ? ebb : nbb;
  int* off = isE ? eoff : noff;
  float* inv = isE ? einv : ninv;
  int* out = isE ? edge_nodes : node_edges;
  int NT = isE ? NE : NN;
  int sh = isE ? ESH : NSH;
  int psh = isE ? 17 : 16;                 // pack shift
  unsigned smask = (1u << psh) - 1u;       // src mask
  int tbase = b << sh;
  int nt = min(1 << sh, NT - tbase);
  int t = threadIdx.x;
  cnt[t] = 0; cnt[t + 256] = 0;
  __syncthreads();
  int s = bb[b], e = bb[b + 1];
  for (int i = s + t; i < e; i += 256) atomicAdd(&cnt[bin[i] >> psh], 1);
  __syncthreads();
  int p = cnt[2 * t] + cnt[2 * t + 1];
  sc[t] = p;
  __syncthreads();
  for (int o = 1; o < 256; o <<= 1) {
    int v = (t >= o) ? sc[t - o] : 0;
    __syncthreads();
    sc[t] += v;
    __syncthreads();
  }
  int pb = (t > 0) ? sc[t - 1] : 0;
  excl[2 * t] = pb;
  excl[2 * t + 1] = pb + cnt[2 * t];
  __syncthreads();
  for (int lt = t; lt < nt; lt += 256) {
    off[tbase + lt] = s + excl[lt];
    int c = cnt[lt];
    inv[tbase + lt] = (c > 0) ? 1.0f / (float)c : 0.0f;
  }
  if (b == NBK - 1 && t == 0) off[NT] = ni;
  __syncthreads();
  cnt[t] = 0; cnt[t + 256] = 0;
  __syncthreads();
  for (int i = s + t; i < e; i += 256) {
    unsigned it = bin[i];
    int lt = it >> psh;
    int pos = s + excl[lt] + atomicAdd(&cnt[lt], 1);
    out[pos] = (int)(it & smask);
  }
}

// ---------------- weights pack (bf16 MFMA B-fragment order) ----------------
__global__ void packw_kernel(const float* __restrict__ w0, const float* __restrict__ w1,
                             const float* __restrict__ w2, const float* __restrict__ w3,
                             short* __restrict__ wp) {
  int gid = blockIdx.x * blockDim.x + threadIdx.x;
  if (gid >= 4 * 16384) return;
  int w = gid >> 14, r = gid & 16383;
  int j = r & 7, lane = (r >> 3) & 63, kk = (r >> 9) & 3, ct = (r >> 11) & 7;
  int k = kk * 32 + (lane >> 4) * 8 + j;
  int c = ct * 16 + (lane & 15);
  const float* W = (w == 0) ? w0 : (w == 1) ? w1 : (w == 2) ? w2 : w3;
  wp[gid] = (short)f2bf(W[k * 128 + c]);
}

// ---------------- cvt: x f32 -> bf16 row-major (streaming) ----------------
__global__ __launch_bounds__(256) void cvtrow_kernel(const float* __restrict__ x,
                                                     uint4* __restrict__ xb) {
  size_t q = (size_t)blockIdx.x * 256 + threadIdx.x;  // one uint4 (8 bf16) per thread
  const float4* xf = (const float4*)x;
  float4 lo = xf[q * 2], hi = xf[q * 2 + 1];
  uint4 o;
  o.x = (f2bf(lo.x) & 0xffffu) | (f2bf(lo.y) << 16);
  o.y = (f2bf(lo.z) & 0xffffu) | (f2bf(lo.w) << 16);
  o.z = (f2bf(hi.x) & 0xffffu) | (f2bf(hi.y) << 16);
  o.w = (f2bf(hi.z) & 0xffffu) | (f2bf(hi.w) << 16);
  xb[q] = o;
}

// ---------------- gather (round-6 proven config): 16 lanes/target, 8-way MLP ----------------
template <bool PRELU, bool OBF>  // OBF: bf16 row out; else f32 row out
__global__ __launch_bounds__(256) void gather_kernel(const uint4* __restrict__ src,
                                                     void* __restrict__ dst,
                                                     const int* __restrict__ off,
                                                     const int* __restrict__ ids,
                                                     const float* __restrict__ inv,
                                                     const float* __restrict__ bias,
                                                     const float* __restrict__ alpha_p, int T) {
  int tgt = blockIdx.x * 16 + (threadIdx.x >> 4);
  if (tgt >= T) return;
  int c = threadIdx.x & 15;
  int s = off[tgt], e = off[tgt + 1];
  float r[8] = {0, 0, 0, 0, 0, 0, 0, 0};
  int i = s;
  for (; i + 8 <= e; i += 8) {
    int idv[8];
#pragma unroll
    for (int u = 0; u < 8; u++) idv[u] = ids[i + u];
    uint4 v[8];
#pragma unroll
    for (int u = 0; u < 8; u++) v[u] = src[(size_t)idv[u] * 16 + c];
#pragma unroll
    for (int u = 0; u < 8; u++) {
      r[0] += bfbits2f(v[u].x << 16); r[1] += bfbits2f(v[u].x & 0xffff0000u);
      r[2] += bfbits2f(v[u].y << 16); r[3] += bfbits2f(v[u].y & 0xffff0000u);
      r[4] += bfbits2f(v[u].z << 16); r[5] += bfbits2f(v[u].z & 0xffff0000u);
      r[6] += bfbits2f(v[u].w << 16); r[7] += bfbits2f(v[u].w & 0xffff0000u);
    }
  }
  for (; i < e; i++) {
    uint4 v = src[(size_t)ids[i] * 16 + c];
    r[0] += bfbits2f(v.x << 16); r[1] += bfbits2f(v.x & 0xffff0000u);
    r[2] += bfbits2f(v.y << 16); r[3] += bfbits2f(v.y & 0xffff0000u);
    r[4] += bfbits2f(v.z << 16); r[5] += bfbits2f(v.z & 0xffff0000u);
    r[6] += bfbits2f(v.w << 16); r[7] += bfbits2f(v.w & 0xffff0000u);
  }
  float scv = inv[tgt];
  float al = PRELU ? *alpha_p : 0.f;
  float b[8] = {0, 0, 0, 0, 0, 0, 0, 0};
  if (bias) {
    float4 b0 = ((const float4*)bias)[c * 2];
    float4 b1 = ((const float4*)bias)[c * 2 + 1];
    b[0] = b0.x; b[1] = b0.y; b[2] = b0.z; b[3] = b0.w;
    b[4] = b1.x; b[5] = b1.y; b[6] = b1.z; b[7] = b1.w;
  }
#pragma unroll
  for (int j = 0; j < 8; j++) {
    float v = r[j] * scv + b[j];
    if constexpr (PRELU) v = (v >= 0.f) ? v : al * v;
    r[j] = v;
  }
  if constexpr (OBF) {
    uint4 o;
    o.x = (f2bf(r[0]) & 0xffffu) | (f2bf(r[1]) << 16);
    o.y = (f2bf(r[2]) & 0xffffu) | (f2bf(r[3]) << 16);
    o.z = (f2bf(r[4]) & 0xffffu) | (f2bf(r[5]) << 16);
    o.w = (f2bf(r[6]) & 0xffffu) | (f2bf(r[7]) << 16);
    ((uint4*)dst)[(size_t)tgt * 16 + c] = o;
  } else {
    float4 o0; o0.x = r[0]; o0.y = r[1]; o0.z = r[2]; o0.w = r[3];
    float4 o1; o1.x = r[4]; o1.y = r[5]; o1.z = r[6]; o1.w = r[7];
    ((float4*)dst)[(size_t)tgt * 32 + c * 2] = o0;
    ((float4*)dst)[(size_t)tgt * 32 + c * 2 + 1] = o1;
  }
}

// ---------------- fused double-GEMM: e = prelu(A@WA); xn = e@WB ----------------
// A row-major bf16 [M][128]. Wave-private LDS transpose between GEMMs (wave w
// owns tile rows w*16..+15; MFMA C fragments stay within the wave's rows) ->
// no barriers. WEF32: also write e as f32 row-major (layer-2 edge output).
template <bool WEF32>
__global__ __launch_bounds__(256) void gemm12_kernel(const short* __restrict__ A,
                                                     const short* __restrict__ wpA,
                                                     const short* __restrict__ wpB,
                                                     const float* __restrict__ alpha_p,
                                                     short* __restrict__ xn,
                                                     float* __restrict__ eoutf, int M) {
  __shared__ short tile[64][136];
  int wave = threadIdx.x >> 6;
  int lane = threadIdx.x & 63;
  int kg = lane >> 4;
  int rloc = lane & 15;
  int base = blockIdx.x * 64;
  int row = base + wave * 16 + rloc;
  float al = *alpha_p;

  bf16x8 a[4];
  if (row < M) {
    const short* arow = A + (size_t)row * 128 + kg * 8;
#pragma unroll
    for (int kk = 0; kk < 4; kk++) a[kk] = *(const bf16x8*)(arow + kk * 32);
  } else {
#pragma unroll
    for (int kk = 0; kk < 4; kk++) a[kk] = bf16x8{0, 0, 0, 0, 0, 0, 0, 0};
  }

  // GEMM1 + prelu -> LDS tile (+ optional f32 e output)
#pragma unroll
  for (int ct = 0; ct < 8; ct++) {
    f32x4 acc = {0.f, 0.f, 0.f, 0.f};
#pragma unroll
    for (int kk = 0; kk < 4; kk++) {
      bf16x8 bfr = *(const bf16x8*)(wpA + ((size_t)(ct * 4 + kk) * 64 + lane) * 8);
      acc = __builtin_amdgcn_mfma_f32_16x16x32_bf16(a[kk], bfr, acc, 0, 0, 0);
    }
    int col = ct * 16 + rloc;
#pragma unroll
    for (int j = 0; j < 4; j++) {
      float v = acc[j];
      v = (v >= 0.f) ? v : al * v;
      int lrow = wave * 16 + kg * 4 + j;
      int grow = base + lrow;
      if (WEF32 && grow < M) eoutf[(size_t)grow * 128 + col] = v;
      tile[lrow][col] = (short)f2bf(v);
    }
  }

  // GEMM2 from wave-private LDS tile -> xn row-major bf16
  bf16x8 a2[4];
#pragma unroll
  for (int kk = 0; kk < 4; kk++)
    a2[kk] = *(const bf16x8*)&tile[wave * 16 + rloc][kg * 8 + kk * 32];
#pragma unroll
  for (int ct = 0; ct < 8; ct++) {
    f32x4 acc = {0.f, 0.f, 0.f, 0.f};
#pragma unroll
    for (int kk = 0; kk < 4; kk++) {
      bf16x8 bfr = *(const bf16x8*)(wpB + ((size_t)(ct * 4 + kk) * 64 + lane) * 8);
      acc = __builtin_amdgcn_mfma_f32_16x16x32_bf16(a2[kk], bfr, acc, 0, 0, 0);
    }
    int col = ct * 16 + rloc;
#pragma unroll
    for (int j = 0; j < 4; j++) {
      int grow = base + wave * 16 + kg * 4 + j;
      if (grow < M) xn[(size_t)grow * 128 + col] = (short)f2bf(acc[j]);
    }
  }
}

extern "C" void kernel_launch(void* const* d_in, const int* in_sizes, int n_in,
                              void* d_out, int out_size, void* d_ws, size_t ws_size,
                              hipStream_t stream) {
  const float* x = (const float*)d_in[0];
  const int* nidx = (const int*)d_in[1];
  int NI = in_sizes[1] / 2;
  const int* eidx = nidx + NI;
  const float* W0 = (const float*)d_in[2];
  const float* W1 = (const float*)d_in[3];
  const float* b0 = (const float*)d_in[4];
  const float* W2 = (const float*)d_in[5];
  const float* W3 = (const float*)d_in[6];
  const float* b1 = (const float*)d_in[7];
  const float* alpha = (const float*)d_in[8];

  char* ws = (char*)d_ws;
  size_t o = 0;
  auto alloc = [&](size_t bytes) { void* p = ws + o; o += (bytes + 255) & ~255ull; return p; };
  int* He = (int*)alloc((size_t)NBK * NBLK * 4);
  int* Hn = (int*)alloc((size_t)NBK * NBLK * 4);
  int* ebb = (int*)alloc((NBK + 1) * 4);
  int* nbb = (int*)alloc((NBK + 1) * 4);
  int* eoff = (int*)alloc((size_t)(NE + 1) * 4);
  int* noff = (int*)alloc((size_t)(NN + 1) * 4);
  float* einv = (float*)alloc((size_t)NE * 4);
  float* ninv = (float*)alloc((size_t)NN * 4);
  int* edge_nodes = (int*)alloc((size_t)NI * 4);
  int* node_edges = (int*)alloc((size_t)NI * 4);
  short* wp = (short*)alloc((size_t)4 * 16384 * 2);
  // arena: packed bins (CSR build, 8MB) alias xb (25.6MB, written after CSR build)
  char* arena = (char*)alloc((size_t)NN * 128 * 2 + (size_t)NE * 128 * 2 * 2);
  unsigned* binE = (unsigned*)arena;
  unsigned* binN = (unsigned*)(arena + (size_t)NI * 4);
  short* xb = (short*)arena;                           // NN x 128 bf16 (x~); n1 aliases later
  short* Ge = (short*)(arena + (size_t)NN * 128 * 2);  // NE x 128 bf16 (aggregated)
  short* xn = (short*)(arena + (size_t)NN * 128 * 2 + (size_t)NE * 128 * 2);  // NE x 128 bf16

  float* outN = (float*)d_out;
  float* outE = outN + (size_t)NN * 128;

  // CSR build (both orientations)
  hist_kernel<<<NBLK, 256, 0, stream>>>(nidx, eidx, NI, He, Hn);
  scanH_kernel<<<2, 256, 0, stream>>>(He, Hn, ebb, nbb, NI);
  scatter_kernel<<<NBLK, 256, 0, stream>>>(nidx, eidx, NI, He, Hn, binE, binN);
  finalize_kernel<<<2 * NBK, 256, 0, stream>>>(binE, binN, ebb, nbb, eoff, noff,
                                               einv, ninv, edge_nodes, node_edges, NI);
  packw_kernel<<<256, 256, 0, stream>>>(W0, W1, W2, W3, wp);
  cvtrow_kernel<<<NN * 128 / 8 / 256, 256, 0, stream>>>(x, (uint4*)xb);

  int gfE = (NE + 63) / 64;   // 782 fused-GEMM blocks
  int ggE = NE / 16;          // 3125 gather blocks
  int ggN = (NN + 15) / 16;   // 6250

  // layer 1 (aggregate-first n2e, transform-first e2n)
  gather_kernel<false, true><<<ggE, 256, 0, stream>>>((const uint4*)xb, Ge, eoff, edge_nodes,
                                                      einv, nullptr, alpha, NE);
  gemm12_kernel<false><<<gfE, 256, 0, stream>>>(Ge, wp + 0 * 16384, wp + 1 * 16384,
                                                alpha, xn, nullptr, NE);
  short* n1 = xb;  // x~ dead after layer-1 e-gather
  gather_kernel<true, true><<<ggN, 256, 0, stream>>>((const uint4*)xn, n1, noff, node_edges,
                                                     ninv, b0, alpha, NN);
  // layer 2
  gather_kernel<false, true><<<ggE, 256, 0, stream>>>((const uint4*)n1, Ge, eoff, edge_nodes,
                                                      einv, nullptr, alpha, NE);
  gemm12_kernel<true><<<gfE, 256, 0, stream>>>(Ge, wp + 2 * 16384, wp + 3 * 16384,
                                               alpha, xn, outE, NE);
  gather_kernel<true, false><<<ggN, 256, 0, stream>>>((const uint4*)xn, outN, noff, node_edges,
                                                      ninv, b1, alpha, NN);
}